// Round 2
// baseline (470.988 us; speedup 1.0000x reference)
//
#include <hip/hip_runtime.h>

// Problem constants (match reference file)
#define N_NODES 2000000
#define N_EDGES 32000000
#define N_OUT   400000          // N_NODES / 5
#define NBUCKET 256             // out-index buckets
#define BSZ     1568            // bucket width: 256*1568 = 401408 >= 400000; local fits 11 bits
#define CAP_BLK 32              // per-block per-bucket LDS staging capacity (u32)
#define CHUNK   16384           // edges per block, phase 1 (256 thr * 4 edges * 16 iters)
#define CAP_BKT 28672           // per-bucket payload capacity (lambda=25000, +23 sigma)
#define KSLICE  4               // phase-2 slices per bucket
#define CNT_STRIDE 16           // pad cursor counters: one per 64B cacheline

typedef int iv4 __attribute__((ext_vector_type(4)));
typedef unsigned uv4 __attribute__((ext_vector_type(4)));

// ---------------------------------------------------------------------------
// Phase 1: bin filtered edges into 256 buckets by out-index.
// Stage u32 = (src << 11) | local in LDS (34 KB -> 4 blocks/CU).
// At flush, gather x[src] (2-deep pipelined, overlaps scattered writes) and
// emit 8B payload entries (value_bits, local). This removes ALL random
// gathers from phase 2, which becomes a pure sequential stream.
// Filter uses the multiplicative-inverse trick: t = d * 0xCCCCCCCD;
// d%5==0  <=>  t <= 0x33333333, and then t == d/5 exactly.
// ---------------------------------------------------------------------------
__global__ __launch_bounds__(256, 4) void p1_bin(
    const int* __restrict__ src,
    const int* __restrict__ dst,
    const float* __restrict__ x,
    unsigned* __restrict__ cnt,        // [NBUCKET * CNT_STRIDE]
    float* __restrict__ overflow,      // [NBUCKET][BSZ]
    uint2* __restrict__ payload)       // [NBUCKET][CAP_BKT] (value_bits, local)
{
    __shared__ unsigned s_cur[NBUCKET];
    __shared__ unsigned s_base[NBUCKET];
    __shared__ unsigned s_stage[NBUCKET][CAP_BLK];

    const int tid = threadIdx.x;
    if (tid < NBUCKET) s_cur[tid] = 0;
    __syncthreads();

    const long long blockStart = (long long)blockIdx.x * CHUNK;
    const int NIT = CHUNK / 1024;   // 16 iterations; 1024 edges per block-iter

    // software-pipelined streaming: prefetch next iter's int4 pair.
    // nontemporal: edges are read exactly once.
    long long b0 = blockStart + (long long)tid * 4;
    bool valid0 = (b0 < N_EDGES);
    iv4 d4 = valid0 ? __builtin_nontemporal_load(reinterpret_cast<const iv4*>(dst + b0)) : (iv4)0;
    iv4 s4 = valid0 ? __builtin_nontemporal_load(reinterpret_cast<const iv4*>(src + b0)) : (iv4)0;

    for (int it = 0; it < NIT; ++it) {
        iv4 nd = (iv4)0, ns = (iv4)0;
        bool nvalid = false;
        if (it + 1 < NIT) {
            const long long bn = blockStart + (long long)(it + 1) * 1024 + tid * 4;
            nvalid = (bn < N_EDGES);
            if (nvalid) {
                nd = __builtin_nontemporal_load(reinterpret_cast<const iv4*>(dst + bn));
                ns = __builtin_nontemporal_load(reinterpret_cast<const iv4*>(src + bn));
            }
        }
        if (valid0) {
#pragma unroll
            for (int j = 0; j < 4; ++j) {
                const unsigned d = (unsigned)d4[j];
                const unsigned t = d * 0xCCCCCCCDu;     // == d/5 when d%5==0
                if (t <= 0x33333333u) {
                    const unsigned g = t;                // 0..399999
                    const unsigned b = g / (unsigned)BSZ;    // 0..255 (magic mul)
                    const unsigned local = g - b * (unsigned)BSZ;
                    const unsigned p = ((unsigned)s4[j] << 11) | local;
                    const unsigned slot = atomicAdd(&s_cur[b], 1u);
                    if (slot < CAP_BLK) {
                        s_stage[b][slot] = p;
                    } else {
                        // rare (~5 sigma): direct device-scope add into overflow row
                        const float v = x[s4[j]];
                        atomicAdd(&overflow[(size_t)b * BSZ + local], v);
                    }
                }
            }
        }
        d4 = nd; s4 = ns; valid0 = nvalid;
    }
    __syncthreads();

    // reserve payload runs: 256 parallel cursor atomics (one 64B line each)
    if (tid < NBUCKET) {
        const unsigned c = min(s_cur[tid], (unsigned)CAP_BLK);
        s_cur[tid] = c;
        s_base[tid] = atomicAdd(&cnt[tid * CNT_STRIDE], c);
    }
    __syncthreads();

    // flush: each wave handles 64 buckets, two per step (32 lanes each).
    // 2-deep pipeline: step i's x-gather is in flight while step i-1 writes.
    const int wave = tid >> 6, lane = tid & 63;
    const int half = lane >> 5, l = lane & 31;

    unsigned pay, pos; bool act; float v;
    {
        const int b = wave * 64 + half;
        const unsigned c = s_cur[b];
        act = ((unsigned)l < c);
        pay = act ? s_stage[b][l] : 0u;
        pos = s_base[b] + (unsigned)l;
        act = act && (pos < (unsigned)CAP_BKT);
        v = x[act ? (pay >> 11) : 0u];
    }
    for (int i = 0; i < 32; ++i) {
        bool nact = false; unsigned npay = 0, npos = 0; float nv = 0.0f;
        if (i + 1 < 32) {
            const int nb = wave * 64 + (i + 1) * 2 + half;
            const unsigned nc = s_cur[nb];
            nact = ((unsigned)l < nc);
            npay = nact ? s_stage[nb][l] : 0u;
            npos = s_base[nb] + (unsigned)l;
            nact = nact && (npos < (unsigned)CAP_BKT);
            nv = x[nact ? (npay >> 11) : 0u];
        }
        if (act) {
            const int b = wave * 64 + i * 2 + half;
            payload[(size_t)b * CAP_BKT + pos] =
                make_uint2(__float_as_uint(v), pay & 2047u);
        }
        act = nact; pay = npay; pos = npos; v = nv;
    }
}

// ---------------------------------------------------------------------------
// Phase 2: per (bucket, slice): pure sequential stream of 8B (value, local)
// entries -> LDS ds_add_f32. No random gathers, no dependent chains.
// 512 threads, 4 blocks/CU = 32 waves/CU.
// ---------------------------------------------------------------------------
__global__ __launch_bounds__(512, 8) void p2_accum(
    const unsigned* __restrict__ cnt,
    const uint2* __restrict__ payload,
    float* __restrict__ partials)
{
    __shared__ float acc[BSZ];
    const int b = blockIdx.x >> 2;        // KSLICE = 4
    const int j = blockIdx.x & 3;
    const int tid = threadIdx.x;

    for (int i = tid; i < BSZ; i += 512) acc[i] = 0.0f;
    __syncthreads();

    unsigned n = cnt[b * CNT_STRIDE];
    if (n > CAP_BKT) n = CAP_BKT;         // safety clamp (never expected)
    // slice bounds rounded down to multiples of 2 entries (16B alignment)
    unsigned beg = ((unsigned)(((unsigned long long)n * j) >> 2)) & ~1u;
    unsigned end = (j == KSLICE - 1) ? n
                 : ((unsigned)(((unsigned long long)n * (j + 1)) >> 2)) & ~1u;
    const uint2* pb = payload + (size_t)b * CAP_BKT;

    // 4 entries (32B) per thread per step: two dwordx4 loads, four LDS adds
    unsigned base = beg + (unsigned)tid * 4u;
    for (; base + 3u < end; base += 512u * 4u) {
        const uv4 A = __builtin_nontemporal_load(
            reinterpret_cast<const uv4*>(pb + base));       // entries base, base+1
        const uv4 B = __builtin_nontemporal_load(
            reinterpret_cast<const uv4*>(pb + base + 2));   // entries base+2, base+3
        __hip_atomic_fetch_add(&acc[A[1] & 2047u], __uint_as_float(A[0]),
                               __ATOMIC_RELAXED, __HIP_MEMORY_SCOPE_WORKGROUP);
        __hip_atomic_fetch_add(&acc[A[3] & 2047u], __uint_as_float(A[2]),
                               __ATOMIC_RELAXED, __HIP_MEMORY_SCOPE_WORKGROUP);
        __hip_atomic_fetch_add(&acc[B[1] & 2047u], __uint_as_float(B[0]),
                               __ATOMIC_RELAXED, __HIP_MEMORY_SCOPE_WORKGROUP);
        __hip_atomic_fetch_add(&acc[B[3] & 2047u], __uint_as_float(B[2]),
                               __ATOMIC_RELAXED, __HIP_MEMORY_SCOPE_WORKGROUP);
    }
    if (base < end) {                     // per-thread ragged tail (< 4 entries)
        const unsigned stop = min(end, base + 4u);
        for (unsigned i = base; i < stop; ++i) {
            const uint2 e = pb[i];
            __hip_atomic_fetch_add(&acc[e.y & 2047u], __uint_as_float(e.x),
                                   __ATOMIC_RELAXED, __HIP_MEMORY_SCOPE_WORKGROUP);
        }
    }
    __syncthreads();

    float* row = partials + ((size_t)b * KSLICE + j) * BSZ;
    for (int i = tid; i < BSZ; i += 512) row[i] = acc[i];
}

// ---------------------------------------------------------------------------
// Phase 3: sum KSLICE partial rows + overflow row, folded affine + 2->4->1
// MLP, write out.
// ---------------------------------------------------------------------------
__global__ __launch_bounds__(256) void p3_out(
    const float* __restrict__ partials,
    const float* __restrict__ overflow,
    const float* __restrict__ w_conv,
    const float* __restrict__ b_conv,
    const float* __restrict__ w1,   // [2,4] row-major
    const float* __restrict__ b1,
    const float* __restrict__ w2,
    const float* __restrict__ b2,
    float* __restrict__ out)
{
    const int i = blockIdx.x * 256 + threadIdx.x;
    if (i >= N_OUT) return;
    const int b = i / BSZ;
    const int local = i - b * BSZ;
    const float* pr = partials + (size_t)b * KSLICE * BSZ + local;
    float s = overflow[(size_t)b * BSZ + local];
#pragma unroll
    for (int r = 0; r < KSLICE; ++r) s += pr[(size_t)r * BSZ];
    const float a = s * w_conv[0] + b_conv[0];
    float rr = b2[0];
#pragma unroll
    for (int jj = 0; jj < 4; ++jj) {
        float t = fmaf(a, w1[jj] + w1[4 + jj], b1[jj]);
        rr = fmaf(fmaxf(t, 0.0f), w2[jj], rr);
    }
    out[i] = rr;
}

// ---------------------------------------------------------------------------
// Fallback (ws too small): direct device-atomic scatter + epilogue.
// ---------------------------------------------------------------------------
__global__ __launch_bounds__(256, 4) void gcn_edge_scatter_dev(
    const int* __restrict__ src,
    const int* __restrict__ dst,
    const float* __restrict__ x,
    float* __restrict__ agg)
{
    const long long base = ((long long)blockIdx.x * blockDim.x + threadIdx.x) * 16;
    if (base >= N_EDGES) return;
    iv4 d4[4], s4[4];
#pragma unroll
    for (int c = 0; c < 4; ++c)
        d4[c] = *(reinterpret_cast<const iv4*>(dst + base) + c);
#pragma unroll
    for (int c = 0; c < 4; ++c)
        s4[c] = *(reinterpret_cast<const iv4*>(src + base) + c);
    int dd[16]; int idx[16]; bool pass[16];
#pragma unroll
    for (int c = 0; c < 4; ++c)
#pragma unroll
        for (int j = 0; j < 4; ++j) {
            const int d = d4[c][j];
            const bool p = (d % 5 == 0);
            dd[c * 4 + j] = d; pass[c * 4 + j] = p;
            idx[c * 4 + j] = p ? s4[c][j] : 0;
        }
    float v[16];
#pragma unroll
    for (int k = 0; k < 16; ++k) v[k] = x[idx[k]];
#pragma unroll
    for (int k = 0; k < 16; ++k)
        if (pass[k]) atomicAdd(&agg[dd[k] / 5], v[k]);
}

__global__ __launch_bounds__(256) void gcn_epilogue_fb(
    const float* __restrict__ agg,
    const float* __restrict__ w_conv, const float* __restrict__ b_conv,
    const float* __restrict__ w1, const float* __restrict__ b1,
    const float* __restrict__ w2, const float* __restrict__ b2,
    float* __restrict__ out)
{
    const int i = blockIdx.x * 256 + threadIdx.x;
    if (i >= N_OUT) return;
    const float a = agg[i] * w_conv[0] + b_conv[0];
    float r = b2[0];
#pragma unroll
    for (int j = 0; j < 4; ++j) {
        float t = fmaf(a, w1[j] + w1[4 + j], b1[j]);
        r = fmaf(fmaxf(t, 0.0f), w2[j], r);
    }
    out[i] = r;
}

extern "C" void kernel_launch(void* const* d_in, const int* in_sizes, int n_in,
                              void* d_out, int out_size, void* d_ws, size_t ws_size,
                              hipStream_t stream) {
    const float* x      = (const float*)d_in[0];
    const int*   ei     = (const int*)  d_in[1];  // [2, N_EDGES]: src row then dst row
    const float* w_conv = (const float*)d_in[2];
    const float* b_conv = (const float*)d_in[3];
    const float* w1     = (const float*)d_in[4];
    const float* b1     = (const float*)d_in[5];
    const float* w2     = (const float*)d_in[6];
    const float* b2     = (const float*)d_in[7];
    float* out = (float*)d_out;

    // ws layout: [cnt 16KB][overflow 1.6MB][partials 6.4MB][payload 58.7MB]
    // Only cnt + overflow need zeroing (p2 fully overwrites partials rows).
    const size_t cnt_bytes = (size_t)NBUCKET * CNT_STRIDE * sizeof(unsigned); // 16384
    const size_t ovf_off   = cnt_bytes;
    const size_t ovf_bytes = (size_t)NBUCKET * BSZ * sizeof(float);           // 1605632
    const size_t part_off  = (ovf_off + ovf_bytes + 255) & ~(size_t)255;
    const size_t part_bytes= (size_t)NBUCKET * KSLICE * BSZ * sizeof(float);  // 6422528
    const size_t pay_off   = (part_off + part_bytes + 255) & ~(size_t)255;
    const size_t pay_bytes = (size_t)NBUCKET * CAP_BKT * sizeof(uint2);       // 58720256
    const size_t need      = pay_off + pay_bytes;

    if (ws_size >= need) {
        unsigned* cnt      = (unsigned*)d_ws;
        float*    overflow = (float*)((char*)d_ws + ovf_off);
        float*    partials = (float*)((char*)d_ws + part_off);
        uint2*    payload  = (uint2*)((char*)d_ws + pay_off);

        (void)hipMemsetAsync(d_ws, 0, ovf_off + ovf_bytes, stream); // cnt + overflow

        const int grid_p1 = (int)((N_EDGES + CHUNK - 1) / CHUNK);   // 1954
        p1_bin<<<grid_p1, 256, 0, stream>>>(ei, ei + N_EDGES, x, cnt, overflow, payload);
        p2_accum<<<NBUCKET * KSLICE, 512, 0, stream>>>(cnt, payload, partials);
        p3_out<<<(N_OUT + 255) / 256, 256, 0, stream>>>(
            partials, overflow, w_conv, b_conv, w1, b1, w2, b2, out);
    } else {
        float* agg = (float*)d_ws;
        (void)hipMemsetAsync(agg, 0, (size_t)N_OUT * sizeof(float), stream);
        gcn_edge_scatter_dev<<<(N_EDGES / 16 + 255) / 256, 256, 0, stream>>>(
            ei, ei + N_EDGES, x, agg);
        gcn_epilogue_fb<<<(N_OUT + 255) / 256, 256, 0, stream>>>(
            agg, w_conv, b_conv, w1, b1, w2, b2, out);
    }
}

// Round 3
// 441.998 us; speedup vs baseline: 1.0656x; 1.0656x over previous
//
#include <hip/hip_runtime.h>

// Problem constants (match reference file)
#define N_NODES 2000000
#define N_EDGES 32000000
#define N_OUT   400000          // N_NODES / 5
#define NBUCKET 256             // out-index buckets
#define BSZ     1568            // bucket width: 256*1568 = 401408 >= 400000; local fits 11 bits
#define CAP_BLK 32              // per-block per-bucket LDS staging capacity (u32)
#define CHUNK   16384           // edges per block, phase 1 (256 thr * 4 edges * 16 iters)
#define CAP_BKT 28672           // per-bucket payload capacity (lambda=25000, +23 sigma)
#define CNT_STRIDE 16           // pad cursor counters: one per 64B cacheline

typedef int iv4 __attribute__((ext_vector_type(4)));
typedef unsigned uv4 __attribute__((ext_vector_type(4)));

// ---------------------------------------------------------------------------
// Phase 1: bin filtered edges into 256 buckets by out-index.
// payload u32 = (src << 11) | local, src < 2^21, local < 1568 < 2^11.
// s_stage row stride is CAP_BLK+1=33 words: with stride 32, bank = slot%32
// regardless of bucket, and since all buckets fill in lockstep the ~13
// active lanes of a wave hit the SAME bank every staging store. Stride 33
// gives bank = (bucket + slot) % 32 -> spread. LDS 35.8 KB -> 4 blocks/CU.
// Filter via multiplicative inverse: t = d * 0xCCCCCCCD;
// d%5==0  <=>  t <= 0x33333333, and then t == d/5 exactly.
// ---------------------------------------------------------------------------
__global__ __launch_bounds__(256, 4) void p1_bin(
    const int* __restrict__ src,
    const int* __restrict__ dst,
    const float* __restrict__ x,
    unsigned* __restrict__ cnt,        // [NBUCKET * CNT_STRIDE]
    float* __restrict__ overflow,      // [NBUCKET][BSZ]
    unsigned* __restrict__ payload)    // [NBUCKET][CAP_BKT]
{
    __shared__ unsigned s_cur[NBUCKET];
    __shared__ unsigned s_base[NBUCKET];
    __shared__ unsigned s_stage[NBUCKET][CAP_BLK + 1];   // stride 33: bank spread

    const int tid = threadIdx.x;
    if (tid < NBUCKET) s_cur[tid] = 0;
    __syncthreads();

    const long long blockStart = (long long)blockIdx.x * CHUNK;
    const int NIT = CHUNK / 1024;   // 16 iterations; 1024 edges per block-iter

    // software-pipelined streaming: prefetch next iter's int4 pair.
    // nontemporal: edges are read exactly once.
    long long b0 = blockStart + (long long)tid * 4;
    bool valid0 = (b0 < N_EDGES);
    iv4 d4 = valid0 ? __builtin_nontemporal_load(reinterpret_cast<const iv4*>(dst + b0)) : (iv4)0;
    iv4 s4 = valid0 ? __builtin_nontemporal_load(reinterpret_cast<const iv4*>(src + b0)) : (iv4)0;

    for (int it = 0; it < NIT; ++it) {
        iv4 nd = (iv4)0, ns = (iv4)0;
        bool nvalid = false;
        if (it + 1 < NIT) {
            const long long bn = blockStart + (long long)(it + 1) * 1024 + tid * 4;
            nvalid = (bn < N_EDGES);
            if (nvalid) {
                nd = __builtin_nontemporal_load(reinterpret_cast<const iv4*>(dst + bn));
                ns = __builtin_nontemporal_load(reinterpret_cast<const iv4*>(src + bn));
            }
        }
        if (valid0) {
#pragma unroll
            for (int j = 0; j < 4; ++j) {
                const unsigned d = (unsigned)d4[j];
                const unsigned t = d * 0xCCCCCCCDu;      // == d/5 when d%5==0
                if (t <= 0x33333333u) {
                    const unsigned g = t;                    // 0..399999
                    const unsigned b = g / (unsigned)BSZ;    // 0..255 (magic mul)
                    const unsigned local = g - b * (unsigned)BSZ;
                    const unsigned p = ((unsigned)s4[j] << 11) | local;
                    const unsigned slot = atomicAdd(&s_cur[b], 1u);
                    if (slot < CAP_BLK) {
                        s_stage[b][slot] = p;
                    } else {
                        // rare (~5 sigma): direct device-scope add into overflow row
                        const float v = x[s4[j]];
                        atomicAdd(&overflow[(size_t)b * BSZ + local], v);
                    }
                }
            }
        }
        d4 = nd; s4 = ns; valid0 = nvalid;
    }
    __syncthreads();

    // reserve payload runs: 256 parallel cursor atomics (one 64B line each)
    if (tid < NBUCKET) {
        const unsigned c = min(s_cur[tid], (unsigned)CAP_BLK);
        s_cur[tid] = c;
        s_base[tid] = atomicAdd(&cnt[tid * CNT_STRIDE], c);
    }
    __syncthreads();

    // flush: each wave handles 64 buckets, two per step (32 lanes each)
    const int wave = tid >> 6, lane = tid & 63;
    const int half = lane >> 5, l = lane & 31;
    for (int i = 0; i < 32; ++i) {
        const int b = wave * 64 + i * 2 + half;
        const unsigned c = s_cur[b];
        const unsigned pos = s_base[b] + (unsigned)l;
        if ((unsigned)l < c && pos < (unsigned)CAP_BKT)
            payload[(size_t)b * CAP_BKT + pos] = s_stage[b][l];
    }
}

// ---------------------------------------------------------------------------
// Phase 2 (fused with epilogue): one 1024-thread block per bucket.
// Stream the bucket's payload (8 entries / 32 B per thread per step,
// nontemporal), gather x 8-deep, ds_add_f32 into the 1568-float LDS
// accumulator, then apply overflow row + folded affine + 2->4->1 MLP and
// write out[b*BSZ ..] directly. No partials buffer, no third kernel.
// ---------------------------------------------------------------------------
__global__ __launch_bounds__(1024, 4) void p2_fused(
    const unsigned* __restrict__ cnt,
    const unsigned* __restrict__ payload,
    const float* __restrict__ x,
    const float* __restrict__ overflow,
    const float* __restrict__ w_conv,
    const float* __restrict__ b_conv,
    const float* __restrict__ w1,   // [2,4] row-major
    const float* __restrict__ b1,
    const float* __restrict__ w2,
    const float* __restrict__ b2,
    float* __restrict__ out)
{
    __shared__ float acc[BSZ];
    const int b = blockIdx.x;
    const int tid = threadIdx.x;

    for (int i = tid; i < BSZ; i += 1024) acc[i] = 0.0f;
    __syncthreads();

    unsigned n = cnt[b * CNT_STRIDE];
    if (n > CAP_BKT) n = CAP_BKT;         // safety clamp (never expected)
    const unsigned* pb = payload + (size_t)b * CAP_BKT;

    // 8 entries (32B) per thread per step: payload loads, then gathers, then adds
    unsigned i0 = (unsigned)tid * 8u;
    for (; i0 + 7u < n; i0 += 1024u * 8u) {
        const uv4 A = __builtin_nontemporal_load(reinterpret_cast<const uv4*>(pb + i0));
        const uv4 B = __builtin_nontemporal_load(reinterpret_cast<const uv4*>(pb + i0 + 4));
        unsigned pv[8];
#pragma unroll
        for (int u = 0; u < 4; ++u) { pv[u] = A[u]; pv[u + 4] = B[u]; }
        float vv[8];
#pragma unroll
        for (int u = 0; u < 8; ++u) vv[u] = x[pv[u] >> 11];
#pragma unroll
        for (int u = 0; u < 8; ++u)
            __hip_atomic_fetch_add(&acc[pv[u] & 2047u], vv[u],
                                   __ATOMIC_RELAXED, __HIP_MEMORY_SCOPE_WORKGROUP);
    }
    if (i0 < n) {                          // one thread's ragged tail (< 8 entries)
        const unsigned stop = min(n, i0 + 8u);
        for (unsigned i = i0; i < stop; ++i) {
            const unsigned p = pb[i];
            __hip_atomic_fetch_add(&acc[p & 2047u], x[p >> 11],
                                   __ATOMIC_RELAXED, __HIP_MEMORY_SCOPE_WORKGROUP);
        }
    }
    __syncthreads();

    // epilogue: overflow add + folded affine + MLP, coalesced out write
    const float wc = w_conv[0], bc = b_conv[0], bb2 = b2[0];
    float w1s[4], bb1[4], ww2[4];
#pragma unroll
    for (int jj = 0; jj < 4; ++jj) {
        w1s[jj] = w1[jj] + w1[4 + jj];
        bb1[jj] = b1[jj];
        ww2[jj] = w2[jj];
    }
    const int gbase = b * BSZ;
    for (int local = tid; local < BSZ; local += 1024) {
        const int gi = gbase + local;
        if (gi < N_OUT) {
            const float s = acc[local] + overflow[(size_t)b * BSZ + local];
            const float a = s * wc + bc;
            float rr = bb2;
#pragma unroll
            for (int jj = 0; jj < 4; ++jj) {
                const float tt = fmaf(a, w1s[jj], bb1[jj]);
                rr = fmaf(fmaxf(tt, 0.0f), ww2[jj], rr);
            }
            out[gi] = rr;
        }
    }
}

// ---------------------------------------------------------------------------
// Fallback (ws too small): direct device-atomic scatter + epilogue.
// ---------------------------------------------------------------------------
__global__ __launch_bounds__(256, 4) void gcn_edge_scatter_dev(
    const int* __restrict__ src,
    const int* __restrict__ dst,
    const float* __restrict__ x,
    float* __restrict__ agg)
{
    const long long base = ((long long)blockIdx.x * blockDim.x + threadIdx.x) * 16;
    if (base >= N_EDGES) return;
    iv4 d4[4], s4[4];
#pragma unroll
    for (int c = 0; c < 4; ++c)
        d4[c] = *(reinterpret_cast<const iv4*>(dst + base) + c);
#pragma unroll
    for (int c = 0; c < 4; ++c)
        s4[c] = *(reinterpret_cast<const iv4*>(src + base) + c);
    int dd[16]; int idx[16]; bool pass[16];
#pragma unroll
    for (int c = 0; c < 4; ++c)
#pragma unroll
        for (int j = 0; j < 4; ++j) {
            const int d = d4[c][j];
            const bool p = (d % 5 == 0);
            dd[c * 4 + j] = d; pass[c * 4 + j] = p;
            idx[c * 4 + j] = p ? s4[c][j] : 0;
        }
    float v[16];
#pragma unroll
    for (int k = 0; k < 16; ++k) v[k] = x[idx[k]];
#pragma unroll
    for (int k = 0; k < 16; ++k)
        if (pass[k]) atomicAdd(&agg[dd[k] / 5], v[k]);
}

__global__ __launch_bounds__(256) void gcn_epilogue_fb(
    const float* __restrict__ agg,
    const float* __restrict__ w_conv, const float* __restrict__ b_conv,
    const float* __restrict__ w1, const float* __restrict__ b1,
    const float* __restrict__ w2, const float* __restrict__ b2,
    float* __restrict__ out)
{
    const int i = blockIdx.x * 256 + threadIdx.x;
    if (i >= N_OUT) return;
    const float a = agg[i] * w_conv[0] + b_conv[0];
    float r = b2[0];
#pragma unroll
    for (int j = 0; j < 4; ++j) {
        float t = fmaf(a, w1[j] + w1[4 + j], b1[j]);
        r = fmaf(fmaxf(t, 0.0f), w2[j], r);
    }
    out[i] = r;
}

extern "C" void kernel_launch(void* const* d_in, const int* in_sizes, int n_in,
                              void* d_out, int out_size, void* d_ws, size_t ws_size,
                              hipStream_t stream) {
    const float* x      = (const float*)d_in[0];
    const int*   ei     = (const int*)  d_in[1];  // [2, N_EDGES]: src row then dst row
    const float* w_conv = (const float*)d_in[2];
    const float* b_conv = (const float*)d_in[3];
    const float* w1     = (const float*)d_in[4];
    const float* b1     = (const float*)d_in[5];
    const float* w2     = (const float*)d_in[6];
    const float* b2     = (const float*)d_in[7];
    float* out = (float*)d_out;

    // ws layout: [cnt 16KB][overflow 1.6MB][payload 25.6MB]
    // Only cnt + overflow need zeroing.
    const size_t cnt_bytes = (size_t)NBUCKET * CNT_STRIDE * sizeof(unsigned); // 16384
    const size_t ovf_off   = cnt_bytes;
    const size_t ovf_bytes = (size_t)NBUCKET * BSZ * sizeof(float);           // 1605632
    const size_t pay_off   = (ovf_off + ovf_bytes + 255) & ~(size_t)255;
    const size_t pay_bytes = (size_t)NBUCKET * CAP_BKT * sizeof(unsigned);    // 29360128
    const size_t need      = pay_off + pay_bytes;

    if (ws_size >= need) {
        unsigned* cnt      = (unsigned*)d_ws;
        float*    overflow = (float*)((char*)d_ws + ovf_off);
        unsigned* payload  = (unsigned*)((char*)d_ws + pay_off);

        (void)hipMemsetAsync(d_ws, 0, ovf_off + ovf_bytes, stream); // cnt + overflow

        const int grid_p1 = (int)((N_EDGES + CHUNK - 1) / CHUNK);   // 1954
        p1_bin<<<grid_p1, 256, 0, stream>>>(ei, ei + N_EDGES, x, cnt, overflow, payload);
        p2_fused<<<NBUCKET, 1024, 0, stream>>>(
            cnt, payload, x, overflow, w_conv, b_conv, w1, b1, w2, b2, out);
    } else {
        float* agg = (float*)d_ws;
        (void)hipMemsetAsync(agg, 0, (size_t)N_OUT * sizeof(float), stream);
        gcn_edge_scatter_dev<<<(N_EDGES / 16 + 255) / 256, 256, 0, stream>>>(
            ei, ei + N_EDGES, x, agg);
        gcn_epilogue_fb<<<(N_OUT + 255) / 256, 256, 0, stream>>>(
            agg, w_conv, b_conv, w1, b1, w2, b2, out);
    }
}

// Round 4
// 436.563 us; speedup vs baseline: 1.0789x; 1.0124x over previous
//
#include <hip/hip_runtime.h>

// Problem constants (match reference file)
#define N_NODES 2000000
#define N_EDGES 32000000
#define N_OUT   400000          // N_NODES / 5
#define NBUCKET 256             // out-index buckets
#define BSZ     1568            // bucket width: 256*1568 = 401408 >= 400000; local fits 11 bits
#define CAP_BLK 32              // per-block per-bucket LDS staging capacity (u32)
#define CHUNK   16384           // edges per block, phase 1 (256 thr * 8 edges * 8 iters)
#define CAP_BKT 28672           // per-bucket payload capacity (lambda=25000, +23 sigma)
#define CNT_STRIDE 16           // pad cursor counters: one per 64B cacheline

typedef int iv4 __attribute__((ext_vector_type(4)));
typedef unsigned uv4 __attribute__((ext_vector_type(4)));

// ---------------------------------------------------------------------------
// Phase 1: bin filtered edges into 256 buckets by out-index.
// payload u32 = (src << 11) | local, src < 2^21, local < 1568 < 2^11.
// Batch-then-commit staging: per iteration each thread classifies 8 edges,
// issues all 8 exec-masked ds_add_rtn cursor atomics back-to-back (slot is
// not consumed until the store loop, so only ONE lgkmcnt wait per iteration
// instead of 8 serialized atomic->wait->store chains), then commits stores.
// s_stage row stride CAP_BLK+1=33: bank = (bucket + slot) % 32 -> spread.
// LDS 35.8 KB -> 4 blocks/CU.
// Filter via multiplicative inverse: t = d * 0xCCCCCCCD;
// d%5==0  <=>  t <= 0x33333333, and then t == d/5 exactly.
// ---------------------------------------------------------------------------
__global__ __launch_bounds__(256, 4) void p1_bin(
    const int* __restrict__ src,
    const int* __restrict__ dst,
    const float* __restrict__ x,
    unsigned* __restrict__ cnt,        // [NBUCKET * CNT_STRIDE]
    float* __restrict__ overflow,      // [NBUCKET][BSZ]
    unsigned* __restrict__ payload)    // [NBUCKET][CAP_BKT]
{
    __shared__ unsigned s_cur[NBUCKET];
    __shared__ unsigned s_base[NBUCKET];
    __shared__ unsigned s_stage[NBUCKET][CAP_BLK + 1];   // stride 33: bank spread

    const int tid = threadIdx.x;
    if (tid < NBUCKET) s_cur[tid] = 0;
    __syncthreads();

    const long long blockStart = (long long)blockIdx.x * CHUNK;
    const int NIT = CHUNK / 2048;   // 8 iterations; 2048 edges (8/thread) per iter

    // software-pipelined streaming: prefetch next iter's two int4 pairs.
    // nontemporal: edges are read exactly once. N_EDGES % 8 == 0, so an
    // 8-edge group is either fully in range or fully out.
    long long b0 = blockStart + (long long)tid * 8;
    bool valid0 = (b0 < N_EDGES);
    iv4 dA = (iv4)0, dB = (iv4)0, sA = (iv4)0, sB = (iv4)0;
    if (valid0) {
        dA = __builtin_nontemporal_load(reinterpret_cast<const iv4*>(dst + b0));
        dB = __builtin_nontemporal_load(reinterpret_cast<const iv4*>(dst + b0 + 4));
        sA = __builtin_nontemporal_load(reinterpret_cast<const iv4*>(src + b0));
        sB = __builtin_nontemporal_load(reinterpret_cast<const iv4*>(src + b0 + 4));
    }

    for (int it = 0; it < NIT; ++it) {
        iv4 ndA = (iv4)0, ndB = (iv4)0, nsA = (iv4)0, nsB = (iv4)0;
        bool nvalid = false;
        if (it + 1 < NIT) {
            const long long bn = blockStart + (long long)(it + 1) * 2048 + tid * 8;
            nvalid = (bn < N_EDGES);
            if (nvalid) {
                ndA = __builtin_nontemporal_load(reinterpret_cast<const iv4*>(dst + bn));
                ndB = __builtin_nontemporal_load(reinterpret_cast<const iv4*>(dst + bn + 4));
                nsA = __builtin_nontemporal_load(reinterpret_cast<const iv4*>(src + bn));
                nsB = __builtin_nontemporal_load(reinterpret_cast<const iv4*>(src + bn + 4));
            }
        }
        if (valid0) {
            // ---- classify all 8 edges (pure VALU, no LDS) ----
            bool     ps[8];
            unsigned bb[8], pp[8];
#pragma unroll
            for (int j = 0; j < 8; ++j) {
                const unsigned d = (unsigned)(j < 4 ? dA[j] : dB[j - 4]);
                const unsigned s = (unsigned)(j < 4 ? sA[j] : sB[j - 4]);
                const unsigned t = d * 0xCCCCCCCDu;      // == d/5 when d%5==0
                ps[j] = (t <= 0x33333333u);
                const unsigned q = t / (unsigned)BSZ;    // magic mul, full-range
                bb[j] = q & 255u;                        // exact for passing lanes
                const unsigned local = t - q * (unsigned)BSZ;   // always < 1568
                pp[j] = (s << 11) | local;
            }
            // ---- issue all cursor atomics back-to-back (slot unused yet) ----
            unsigned slot[8];
#pragma unroll
            for (int j = 0; j < 8; ++j)
                if (ps[j]) slot[j] = atomicAdd(&s_cur[bb[j]], 1u);
            // ---- commit: one lgkmcnt wait covers all 8 atomics ----
#pragma unroll
            for (int j = 0; j < 8; ++j) {
                if (ps[j]) {
                    if (slot[j] < CAP_BLK) {
                        s_stage[bb[j]][slot[j]] = pp[j];
                    } else {
                        // rare (~5 sigma): direct device-scope add into overflow row
                        atomicAdd(&overflow[(size_t)bb[j] * BSZ + (pp[j] & 2047u)],
                                  x[pp[j] >> 11]);
                    }
                }
            }
        }
        dA = ndA; dB = ndB; sA = nsA; sB = nsB; valid0 = nvalid;
    }
    __syncthreads();

    // reserve payload runs: 256 parallel cursor atomics (one 64B line each)
    if (tid < NBUCKET) {
        const unsigned c = min(s_cur[tid], (unsigned)CAP_BLK);
        s_cur[tid] = c;
        s_base[tid] = atomicAdd(&cnt[tid * CNT_STRIDE], c);
    }
    __syncthreads();

    // flush: each wave handles 64 buckets, two per step (32 lanes each)
    const int wave = tid >> 6, lane = tid & 63;
    const int half = lane >> 5, l = lane & 31;
    for (int i = 0; i < 32; ++i) {
        const int b = wave * 64 + i * 2 + half;
        const unsigned c = s_cur[b];
        const unsigned pos = s_base[b] + (unsigned)l;
        if ((unsigned)l < c && pos < (unsigned)CAP_BKT)
            payload[(size_t)b * CAP_BKT + pos] = s_stage[b][l];
    }
}

// ---------------------------------------------------------------------------
// Phase 2 (fused with epilogue): one 1024-thread block per bucket.
// 2-deep pipelined payload stream (next batch's 32B loads issue before the
// current batch's gathers), gather x 8-deep, ds_add_f32 into the 1568-float
// LDS accumulator, then overflow row + folded affine + 2->4->1 MLP, write
// out[b*BSZ ..] directly.
// ---------------------------------------------------------------------------
__global__ __launch_bounds__(1024, 4) void p2_fused(
    const unsigned* __restrict__ cnt,
    const unsigned* __restrict__ payload,
    const float* __restrict__ x,
    const float* __restrict__ overflow,
    const float* __restrict__ w_conv,
    const float* __restrict__ b_conv,
    const float* __restrict__ w1,   // [2,4] row-major
    const float* __restrict__ b1,
    const float* __restrict__ w2,
    const float* __restrict__ b2,
    float* __restrict__ out)
{
    __shared__ float acc[BSZ];
    const int b = blockIdx.x;
    const int tid = threadIdx.x;

    for (int i = tid; i < BSZ; i += 1024) acc[i] = 0.0f;
    __syncthreads();

    unsigned n = cnt[b * CNT_STRIDE];
    if (n > CAP_BKT) n = CAP_BKT;         // safety clamp (never expected)
    const unsigned* pb = payload + (size_t)b * CAP_BKT;

    // 8 entries (32B) per thread per step, 2-deep software pipeline
    unsigned i0 = (unsigned)tid * 8u;
    uv4 A = {}, B = {};
    bool cur = (i0 + 7u < n);
    if (cur) {
        A = __builtin_nontemporal_load(reinterpret_cast<const uv4*>(pb + i0));
        B = __builtin_nontemporal_load(reinterpret_cast<const uv4*>(pb + i0 + 4));
    }
    while (cur) {
        const unsigned i1 = i0 + 1024u * 8u;
        uv4 nA = {}, nB = {};
        const bool nxt = (i1 + 7u < n);
        if (nxt) {
            nA = __builtin_nontemporal_load(reinterpret_cast<const uv4*>(pb + i1));
            nB = __builtin_nontemporal_load(reinterpret_cast<const uv4*>(pb + i1 + 4));
        }
        unsigned pv[8];
#pragma unroll
        for (int u = 0; u < 4; ++u) { pv[u] = A[u]; pv[u + 4] = B[u]; }
        float vv[8];
#pragma unroll
        for (int u = 0; u < 8; ++u) vv[u] = x[pv[u] >> 11];
#pragma unroll
        for (int u = 0; u < 8; ++u)
            __hip_atomic_fetch_add(&acc[pv[u] & 2047u], vv[u],
                                   __ATOMIC_RELAXED, __HIP_MEMORY_SCOPE_WORKGROUP);
        A = nA; B = nB; i0 = i1; cur = nxt;
    }
    if (i0 < n) {                          // per-thread ragged tail (< 8 entries)
        const unsigned stop = min(n, i0 + 8u);
        for (unsigned i = i0; i < stop; ++i) {
            const unsigned p = pb[i];
            __hip_atomic_fetch_add(&acc[p & 2047u], x[p >> 11],
                                   __ATOMIC_RELAXED, __HIP_MEMORY_SCOPE_WORKGROUP);
        }
    }
    __syncthreads();

    // epilogue: overflow add + folded affine + MLP, coalesced out write
    const float wc = w_conv[0], bc = b_conv[0], bb2 = b2[0];
    float w1s[4], bb1[4], ww2[4];
#pragma unroll
    for (int jj = 0; jj < 4; ++jj) {
        w1s[jj] = w1[jj] + w1[4 + jj];
        bb1[jj] = b1[jj];
        ww2[jj] = w2[jj];
    }
    const int gbase = b * BSZ;
    for (int local = tid; local < BSZ; local += 1024) {
        const int gi = gbase + local;
        if (gi < N_OUT) {
            const float s = acc[local] + overflow[(size_t)b * BSZ + local];
            const float a = s * wc + bc;
            float rr = bb2;
#pragma unroll
            for (int jj = 0; jj < 4; ++jj) {
                const float tt = fmaf(a, w1s[jj], bb1[jj]);
                rr = fmaf(fmaxf(tt, 0.0f), ww2[jj], rr);
            }
            out[gi] = rr;
        }
    }
}

// ---------------------------------------------------------------------------
// Fallback (ws too small): direct device-atomic scatter + epilogue.
// ---------------------------------------------------------------------------
__global__ __launch_bounds__(256, 4) void gcn_edge_scatter_dev(
    const int* __restrict__ src,
    const int* __restrict__ dst,
    const float* __restrict__ x,
    float* __restrict__ agg)
{
    const long long base = ((long long)blockIdx.x * blockDim.x + threadIdx.x) * 16;
    if (base >= N_EDGES) return;
    iv4 d4[4], s4[4];
#pragma unroll
    for (int c = 0; c < 4; ++c)
        d4[c] = *(reinterpret_cast<const iv4*>(dst + base) + c);
#pragma unroll
    for (int c = 0; c < 4; ++c)
        s4[c] = *(reinterpret_cast<const iv4*>(src + base) + c);
    int dd[16]; int idx[16]; bool pass[16];
#pragma unroll
    for (int c = 0; c < 4; ++c)
#pragma unroll
        for (int j = 0; j < 4; ++j) {
            const int d = d4[c][j];
            const bool p = (d % 5 == 0);
            dd[c * 4 + j] = d; pass[c * 4 + j] = p;
            idx[c * 4 + j] = p ? s4[c][j] : 0;
        }
    float v[16];
#pragma unroll
    for (int k = 0; k < 16; ++k) v[k] = x[idx[k]];
#pragma unroll
    for (int k = 0; k < 16; ++k)
        if (pass[k]) atomicAdd(&agg[dd[k] / 5], v[k]);
}

__global__ __launch_bounds__(256) void gcn_epilogue_fb(
    const float* __restrict__ agg,
    const float* __restrict__ w_conv, const float* __restrict__ b_conv,
    const float* __restrict__ w1, const float* __restrict__ b1,
    const float* __restrict__ w2, const float* __restrict__ b2,
    float* __restrict__ out)
{
    const int i = blockIdx.x * 256 + threadIdx.x;
    if (i >= N_OUT) return;
    const float a = agg[i] * w_conv[0] + b_conv[0];
    float r = b2[0];
#pragma unroll
    for (int j = 0; j < 4; ++j) {
        float t = fmaf(a, w1[j] + w1[4 + j], b1[j]);
        r = fmaf(fmaxf(t, 0.0f), w2[j], r);
    }
    out[i] = r;
}

extern "C" void kernel_launch(void* const* d_in, const int* in_sizes, int n_in,
                              void* d_out, int out_size, void* d_ws, size_t ws_size,
                              hipStream_t stream) {
    const float* x      = (const float*)d_in[0];
    const int*   ei     = (const int*)  d_in[1];  // [2, N_EDGES]: src row then dst row
    const float* w_conv = (const float*)d_in[2];
    const float* b_conv = (const float*)d_in[3];
    const float* w1     = (const float*)d_in[4];
    const float* b1     = (const float*)d_in[5];
    const float* w2     = (const float*)d_in[6];
    const float* b2     = (const float*)d_in[7];
    float* out = (float*)d_out;

    // ws layout: [cnt 16KB][overflow 1.6MB][payload 25.6MB]
    // Only cnt + overflow need zeroing.
    const size_t cnt_bytes = (size_t)NBUCKET * CNT_STRIDE * sizeof(unsigned); // 16384
    const size_t ovf_off   = cnt_bytes;
    const size_t ovf_bytes = (size_t)NBUCKET * BSZ * sizeof(float);           // 1605632
    const size_t pay_off   = (ovf_off + ovf_bytes + 255) & ~(size_t)255;
    const size_t pay_bytes = (size_t)NBUCKET * CAP_BKT * sizeof(unsigned);    // 29360128
    const size_t need      = pay_off + pay_bytes;

    if (ws_size >= need) {
        unsigned* cnt      = (unsigned*)d_ws;
        float*    overflow = (float*)((char*)d_ws + ovf_off);
        unsigned* payload  = (unsigned*)((char*)d_ws + pay_off);

        (void)hipMemsetAsync(d_ws, 0, ovf_off + ovf_bytes, stream); // cnt + overflow

        const int grid_p1 = (int)((N_EDGES + CHUNK - 1) / CHUNK);   // 1954
        p1_bin<<<grid_p1, 256, 0, stream>>>(ei, ei + N_EDGES, x, cnt, overflow, payload);
        p2_fused<<<NBUCKET, 1024, 0, stream>>>(
            cnt, payload, x, overflow, w_conv, b_conv, w1, b1, w2, b2, out);
    } else {
        float* agg = (float*)d_ws;
        (void)hipMemsetAsync(agg, 0, (size_t)N_OUT * sizeof(float), stream);
        gcn_edge_scatter_dev<<<(N_EDGES / 16 + 255) / 256, 256, 0, stream>>>(
            ei, ei + N_EDGES, x, agg);
        gcn_epilogue_fb<<<(N_OUT + 255) / 256, 256, 0, stream>>>(
            agg, w_conv, b_conv, w1, b1, w2, b2, out);
    }
}